// Round 15
// baseline (169.288 us; speedup 1.0000x reference)
//
#include <hip/hip_runtime.h>

typedef _Float16 h2 __attribute__((ext_vector_type(2)));

#define GRID_W 4
#define GRID_H 4
#define NEXP   16
#define HID    256
#define TPB    512
#define S      2
#define SAMP   (TPB * S)        // 1024 samples per block
#define NWAVE  (TPB / 64)       // 8 waves
#define GR     64               // entry granularity: 1 sub-wave per entry
#define MAXENT 33               // 16 + 1024/64 (+1)

#define CAPP   88               // pairs per mixed array (176 cap; e=0 ~128+-8)
#define HPA    (2 * CAPP)       // halves per array   = 176
#define HPE    (6 * HPA)        // halves per expert  = 1056
#define F4PA   (CAPP / 4)       // float4 per array   = 22
#define F4PE   (6 * F4PA)       // float4 per expert  = 132

#define MAGIC  0x13579BDF

// ---- ws layout (bytes) ----
// [0,     768): float aff[16][12]
// [768,   832): int   m2[16]      4-pair batch counts
// [1024, 34816): _Float16 mix[16][1056]
// [35840, 35904): int flags[16]   MAGIC when expert e published (poison!=MAGIC)
#define WSOFF_M2  768
#define WSOFF_MIX 1024
#define WSOFF_FLG 35840

// ---- LDS (~9.3 KB) ----
#define NSLOT  (SAMP + GR)
#define OFFB_I (NSLOT * 8)
#define LDS_BYTES (OFFB_I + 4 * (16 + 17 + 17 + 3 * MAXENT + 1))

union H8 { float4 f; h2 p[4]; };

// ---------------------------------------------------------------------------
// Single dispatch. Blocks 0..15: wave 0 additionally classifies expert
// blockIdx.x (always-on -> fp32 affine fold; mixed -> ballot-packed fp16 list;
// off -> dropped) into ws, then release-stores a flag. All blocks: counting
// sort in LDS (no ws dependency), acquire-spin on the 16 flags (set long
// before consumers arrive), then expert-uniform phase-2 with s_load weights.
// Co-residency guaranteed: __launch_bounds__(512,4) => >=2 blocks/CU => all
// 512 blocks resident => prep blocks always run => no deadlock (G16-safe).
// ---------------------------------------------------------------------------
__global__ __launch_bounds__(TPB, 4) void fused_moe_kernel(
    const float2* __restrict__ samples,
    const float*  __restrict__ W1, const float* __restrict__ b1,
    const float*  __restrict__ W2, const float* __restrict__ b2,
    float* __restrict__ wsAff, int* __restrict__ wsM2,
    _Float16* __restrict__ wsMix, int* __restrict__ wsFlg,
    float* __restrict__ out, int N)
{
    extern __shared__ __align__(16) char smem[];
    int2* sSlot = (int2*)smem;
    int*  sI    = (int*)(smem + OFFB_I);
    int* sHist = sI;                 // [16]
    int* sOff  = sI + 16;            // [17]
    int* sES   = sI + 33;            // [17]
    int* sEexp = sI + 50;            // [33]
    int* sEbas = sI + 50 + MAXENT;
    int* sEcnt = sI + 50 + 2 * MAXENT;
    int* sC    = sI + 50 + 3 * MAXENT;

    const int tid = threadIdx.x;
    const int lane = tid & 63, wv = tid >> 6;
    if (tid < NEXP) sHist[tid] = 0;

    // ---- PREP: blocks 0..15, wave 0 only (other 7 waves go straight to S1) ----
    if (blockIdx.x < NEXP && wv == 0) {
        const int e = blockIdx.x;
        float aff[9] = {0.f,0.f,0.f,0.f,0.f,0.f,0.f,0.f,0.f};
        int basep = 0;
        _Float16* mb = wsMix + e * HPE;
        int ci = e & 3, cj = e >> 2;
        float x0 = ci * 0.25f, x1 = x0 + 0.25f;
        float y0c = cj * 0.25f, y1c = y0c + 0.25f;
#pragma unroll
        for (int kc = 0; kc < 4; ++kc) {
            int k = kc * 64 + lane;
            float a  = W1[e * 512 + k];
            float b  = W1[e * 512 + 256 + k];
            float c  = b1[e * 256 + k];
            float u0 = W2[e * 768 + 3 * k];
            float u1 = W2[e * 768 + 3 * k + 1];
            float u2 = W2[e * 768 + 3 * k + 2];
            float vmin = fminf(a * x0, a * x1) + fminf(b * y0c, b * y1c) + c;
            float vmax = fmaxf(a * x0, a * x1) + fmaxf(b * y0c, b * y1c) + c;
            bool on = vmin >= 0.f;
            bool mixed = (!on) && (vmax > 0.f);
            if (on) {
                aff[0] += u0 * a; aff[1] += u0 * b; aff[2] += u0 * c;
                aff[3] += u1 * a; aff[4] += u1 * b; aff[5] += u1 * c;
                aff[6] += u2 * a; aff[7] += u2 * b; aff[8] += u2 * c;
            }
            unsigned long long mk = __ballot(mixed);
            int pos = basep + __popcll(mk & ((1ull << lane) - 1ull));
            if (mixed && pos < HPA) {
                mb[pos]           = (_Float16)a;
                mb[HPA + pos]     = (_Float16)b;
                mb[2 * HPA + pos] = (_Float16)c;
                mb[3 * HPA + pos] = (_Float16)u0;
                mb[4 * HPA + pos] = (_Float16)u1;
                mb[5 * HPA + pos] = (_Float16)u2;
            }
            basep += __popcll(mk);
        }
        if (basep > HPA) basep = HPA;             // capacity clamp
        int padTo = (basep + 7) & ~7;             // pad to 4-pair multiple
        int idx = basep + lane;
        if (idx < padTo) {
            _Float16 z = (_Float16)0.f;
            mb[idx] = z; mb[HPA + idx] = z; mb[2 * HPA + idx] = z;
            mb[3 * HPA + idx] = z; mb[4 * HPA + idx] = z; mb[5 * HPA + idx] = z;
        }
#pragma unroll
        for (int j = 0; j < 9; ++j) {             // butterfly wave-reduce
            float v = aff[j];
            for (int d = 1; d < 64; d <<= 1) v += __shfl_xor(v, d);
            aff[j] = v;
        }
        if (lane == 0) {
            float* af = wsAff + e * 12;
            af[0] = aff[0]; af[1] = aff[1]; af[2] = aff[2] + b2[3 * e];
            af[3] = aff[3]; af[4] = aff[4]; af[5] = aff[5] + b2[3 * e + 1];
            af[6] = aff[6]; af[7] = aff[7]; af[8] = aff[8] + b2[3 * e + 2];
            af[9] = 0.f; af[10] = 0.f; af[11] = 0.f;
            wsM2[e] = padTo >> 3;                 // 4-pair batch count
            // release: wave-wide vmcnt(0) before the atomic orders ALL lanes'
            // prior global stores; agent scope handles cross-XCD L2.
            __hip_atomic_store(&wsFlg[e], MAGIC, __ATOMIC_RELEASE,
                               __HIP_MEMORY_SCOPE_AGENT);
        }
    }
    __syncthreads();

    // ---- S1: load samples, LDS histogram ----
    const int base0 = blockIdx.x * SAMP;
    float px[S], py[S]; int eid[S], rank[S], gid[S]; bool act[S];
#pragma unroll
    for (int s = 0; s < S; ++s) {
        gid[s] = base0 + s * TPB + tid;           // coalesced float2
        act[s] = gid[s] < N;
        float2 p = act[s] ? samples[gid[s]] : make_float2(0.f, 0.f);
        px[s] = p.x; py[s] = p.y;
        int i = (int)(p.x * (float)GRID_W); i = i < 0 ? 0 : (i > GRID_W - 1 ? GRID_W - 1 : i);
        int j = (int)(p.y * (float)GRID_H); j = j < 0 ? 0 : (j > GRID_H - 1 ? GRID_H - 1 : j);
        eid[s] = j * GRID_W + i;
        rank[s] = act[s] ? atomicAdd(&sHist[eid[s]], 1) : 0;
    }
    __syncthreads();

    // ---- S2: parallel scans in wave 0 ----
    if (wv == 0) {
        int h  = (lane < NEXP) ? sHist[lane] : 0;
        int ec = (lane < NEXP) ? ((h + 63) >> 6) : 0;
        int sh = h, se = ec;
#pragma unroll
        for (int d = 1; d < 16; d <<= 1) {
            int th = __shfl_up(sh, d), te = __shfl_up(se, d);
            if (lane >= d) { sh += th; se += te; }
        }
        if (lane < NEXP) { sOff[lane] = sh - h; sES[lane] = se - ec; }
        if (lane == NEXP - 1) { sOff[NEXP] = sh; sES[NEXP] = se; *sC = se; }
    }
    __syncthreads();

    // ---- S3: scatter sorted slots {h2(x,y), gid} + entry table ----
#pragma unroll
    for (int s = 0; s < S; ++s) {
        if (act[s]) {
            union { h2 h; int i; } u;
            u.h.x = (_Float16)px[s]; u.h.y = (_Float16)py[s];
            int2 v; v.x = u.i; v.y = gid[s];
            sSlot[sOff[eid[s]] + rank[s]] = v;
        }
    }
    int C = *sC;
    if (tid < C) {
        int e = 0;
        while (tid >= sES[e + 1]) ++e;            // <=16 iters, once
        int j = tid - sES[e];
        sEexp[tid] = e;
        sEbas[tid] = sOff[e] + j * GR;
        sEcnt[tid] = min(GR, sHist[e] - j * GR);
    }
    __syncthreads();

    // ---- Wait for all 16 experts published (normally already done) ----
    if (lane < NEXP) {
        while (__hip_atomic_load(&wsFlg[lane], __ATOMIC_ACQUIRE,
                                 __HIP_MEMORY_SCOPE_AGENT) != MAGIC) {}
    }

    // ---- Phase 2: one entry = one expert-uniform sub-wave; weights via
    // wave-uniform s_load from ws ----
    for (int c = wv; c < C; c += NWAVE) {
        int e   = __builtin_amdgcn_readfirstlane(sEexp[c]);
        int bas = __builtin_amdgcn_readfirstlane(sEbas[c]);
        int cnt = __builtin_amdgcn_readfirstlane(sEcnt[c]);

        int2 v = sSlot[bas + lane];               // padded region: in-bounds
        union { int i; h2 h; } uxy; uxy.i = v.x;
        float x = (float)uxy.h.x, y = (float)uxy.h.y;
        int qg = v.y;

        const float* af = wsAff + e * 12;         // uniform -> s_load
        float y0 = fmaf(x, af[0], fmaf(y, af[1], af[2]));
        float y1 = fmaf(x, af[3], fmaf(y, af[4], af[5]));
        float y2 = fmaf(x, af[6], fmaf(y, af[7], af[8]));

        h2 px2; px2.x = uxy.h.x; px2.y = uxy.h.x;
        h2 py2; py2.x = uxy.h.y; py2.y = uxy.h.y;

        int nb = __builtin_amdgcn_readfirstlane(wsM2[e]);
        const float4* Wm = (const float4*)wsMix + e * F4PE;
        for (int bi = 0; bi < nb; ++bi) {
            H8 A, B, Cc, U0, U1, U2;
            A.f  = Wm[bi];
            B.f  = Wm[F4PA + bi];
            Cc.f = Wm[2 * F4PA + bi];
            U0.f = Wm[3 * F4PA + bi];
            U1.f = Wm[4 * F4PA + bi];
            U2.f = Wm[5 * F4PA + bi];
#pragma unroll
            for (int j = 0; j < 4; ++j) {
                h2 h = __builtin_elementwise_fma(px2, A.p[j],
                       __builtin_elementwise_fma(py2, B.p[j], Cc.p[j]));
                h2 z = (h2)(_Float16)0.0f;
                h = __builtin_elementwise_max(h, z);
#if __has_builtin(__builtin_amdgcn_fdot2)
                y0 = __builtin_amdgcn_fdot2(h, U0.p[j], y0, false);
                y1 = __builtin_amdgcn_fdot2(h, U1.p[j], y1, false);
                y2 = __builtin_amdgcn_fdot2(h, U2.p[j], y2, false);
#else
                y0 += (float)h.x * (float)U0.p[j].x + (float)h.y * (float)U0.p[j].y;
                y1 += (float)h.x * (float)U1.p[j].x + (float)h.y * (float)U1.p[j].y;
                y2 += (float)h.x * (float)U2.p[j].x + (float)h.y * (float)U2.p[j].y;
#endif
            }
        }

        if (lane < cnt) {                         // guard sub-wave padding
            int d = 3 * qg;
            out[d + 0] = y0; out[d + 1] = y1; out[d + 2] = y2;
        }
    }
}

// ---------------------------------------------------------------------------
extern "C" void kernel_launch(void* const* d_in, const int* in_sizes, int n_in,
                              void* d_out, int out_size, void* d_ws, size_t ws_size,
                              hipStream_t stream) {
    const float* samples = (const float*)d_in[0];
    const float* W1      = (const float*)d_in[1];
    const float* b1      = (const float*)d_in[2];
    const float* W2      = (const float*)d_in[3];
    const float* b2      = (const float*)d_in[4];
    float* out = (float*)d_out;

    const int N = in_sizes[0] / 2;
    float*    wsAff = (float*)d_ws;
    int*      wsM2  = (int*)((char*)d_ws + WSOFF_M2);
    _Float16* wsMix = (_Float16*)((char*)d_ws + WSOFF_MIX);
    int*      wsFlg = (int*)((char*)d_ws + WSOFF_FLG);

    int nblocks = (N + SAMP - 1) / SAMP;          // 512 @ N=524288
    if (nblocks < NEXP) nblocks = NEXP;           // prep blocks must exist

    fused_moe_kernel<<<nblocks, TPB, LDS_BYTES, stream>>>(
        (const float2*)samples, W1, b1, W2, b2,
        wsAff, wsM2, wsMix, wsFlg, out, N);
}

// Round 16
// 77.126 us; speedup vs baseline: 2.1950x; 2.1950x over previous
//
#include <hip/hip_runtime.h>

typedef _Float16 h2 __attribute__((ext_vector_type(2)));

#define GRID_W 4
#define GRID_H 4
#define NEXP   16
#define HID    256
#define TPB    512
#define S      2
#define SAMP   (TPB * S)        // 1024 samples per block
#define NWAVE  (TPB / 64)       // 8 waves
#define GR     64               // entry granularity: 1 sub-wave per entry
#define MAXENT 33               // 16 + 1024/64 (+1)

#define CAPP   88               // pairs per mixed array (176 cap; e=0 ~128+-8)
#define HPA    (2 * CAPP)       // halves per array   = 176
#define HPE    (6 * HPA)        // halves per expert  = 1056
#define F4PA   (CAPP / 4)       // float4 per array   = 22
#define F4PE   (6 * F4PA)       // float4 per expert  = 132

// ---- ws layout (bytes) ----
// [0,    768): float aff[16][12]
// [768,  832): int   m2[16]        4-pair batch counts
// [1024, 34816): _Float16 mix[16][1056]  6 arrays x 176 halves per expert
#define WSOFF_M2  768
#define WSOFF_MIX 1024

// ---- main-kernel LDS (~9.3 KB) ----
#define NSLOT  (SAMP + GR)
#define OFFB_I (NSLOT * 8)
#define LDS_BYTES (OFFB_I + 4 * (16 + 17 + 17 + 3 * MAXENT + 1))

union H8 { float4 f; h2 p[4]; };

// ---------------------------------------------------------------------------
// Prep: one wave per expert. Classify relu(ax+by+c) over the expert's cell:
// always-on -> fp32 affine fold (butterfly-reduced); mixed -> ballot-prefix
// packed fp16 list (k-order, zero-padded to 4-pair multiple); off -> dropped.
// Separate tiny dispatch: R15 proved in-kernel flag hand-off (spin on one
// agent-scope line) collapses to 130+ us — stream ordering is the cheap sync.
// ---------------------------------------------------------------------------
__global__ __launch_bounds__(64) void prep_kernel(
    const float* __restrict__ W1, const float* __restrict__ b1,
    const float* __restrict__ W2, const float* __restrict__ b2,
    float* __restrict__ wsAff, int* __restrict__ wsM2,
    _Float16* __restrict__ wsMix) {
    const int e = blockIdx.x, lane = threadIdx.x;
    float aff[9] = {0.f,0.f,0.f,0.f,0.f,0.f,0.f,0.f,0.f};
    int basep = 0;
    _Float16* mb = wsMix + e * HPE;
    int ci = e & 3, cj = e >> 2;
    float x0 = ci * 0.25f, x1 = x0 + 0.25f;
    float y0c = cj * 0.25f, y1c = y0c + 0.25f;
#pragma unroll
    for (int kc = 0; kc < 4; ++kc) {
        int k = kc * 64 + lane;
        float a  = W1[e * 512 + k];
        float b  = W1[e * 512 + 256 + k];
        float c  = b1[e * 256 + k];
        float u0 = W2[e * 768 + 3 * k];
        float u1 = W2[e * 768 + 3 * k + 1];
        float u2 = W2[e * 768 + 3 * k + 2];
        float vmin = fminf(a * x0, a * x1) + fminf(b * y0c, b * y1c) + c;
        float vmax = fmaxf(a * x0, a * x1) + fmaxf(b * y0c, b * y1c) + c;
        bool on = vmin >= 0.f;
        bool mixed = (!on) && (vmax > 0.f);
        if (on) {
            aff[0] += u0 * a; aff[1] += u0 * b; aff[2] += u0 * c;
            aff[3] += u1 * a; aff[4] += u1 * b; aff[5] += u1 * c;
            aff[6] += u2 * a; aff[7] += u2 * b; aff[8] += u2 * c;
        }
        unsigned long long mk = __ballot(mixed);
        int pos = basep + __popcll(mk & ((1ull << lane) - 1ull));
        if (mixed && pos < HPA) {
            mb[pos]           = (_Float16)a;
            mb[HPA + pos]     = (_Float16)b;
            mb[2 * HPA + pos] = (_Float16)c;
            mb[3 * HPA + pos] = (_Float16)u0;
            mb[4 * HPA + pos] = (_Float16)u1;
            mb[5 * HPA + pos] = (_Float16)u2;
        }
        basep += __popcll(mk);
    }
    if (basep > HPA) basep = HPA;                 // capacity clamp
    int padTo = (basep + 7) & ~7;                 // pad to 4-pair multiple
    int idx = basep + lane;
    if (idx < padTo) {
        _Float16 z = (_Float16)0.f;
        mb[idx] = z; mb[HPA + idx] = z; mb[2 * HPA + idx] = z;
        mb[3 * HPA + idx] = z; mb[4 * HPA + idx] = z; mb[5 * HPA + idx] = z;
    }
#pragma unroll
    for (int j = 0; j < 9; ++j) {                 // butterfly wave-reduce
        float v = aff[j];
        for (int d = 1; d < 64; d <<= 1) v += __shfl_xor(v, d);
        aff[j] = v;
    }
    if (lane == 0) {
        float* af = wsAff + e * 12;
        af[0] = aff[0]; af[1] = aff[1]; af[2] = aff[2] + b2[3 * e];
        af[3] = aff[3]; af[4] = aff[4]; af[5] = aff[5] + b2[3 * e + 1];
        af[6] = aff[6]; af[7] = aff[7]; af[8] = aff[8] + b2[3 * e + 2];
        af[9] = 0.f; af[10] = 0.f; af[11] = 0.f;
        wsM2[e] = padTo >> 3;                     // 4-pair batch count
    }
}

// ---------------------------------------------------------------------------
// Main kernel: in-block counting sort (tiny LDS) -> expert-uniform sub-waves
// -> affine + mixed-k fp16 loop with s_load weights from ws -> direct stores.
// ---------------------------------------------------------------------------
__global__ __launch_bounds__(TPB, 8) void fused_moe_kernel(
    const float2* __restrict__ samples,
    const float* __restrict__ wsAff, const int* __restrict__ wsM2,
    const _Float16* __restrict__ wsMix,
    float* __restrict__ out, int N)
{
    extern __shared__ __align__(16) char smem[];
    int2* sSlot = (int2*)smem;
    int*  sI    = (int*)(smem + OFFB_I);
    int* sHist = sI;                 // [16]
    int* sOff  = sI + 16;            // [17]
    int* sES   = sI + 33;            // [17]
    int* sEexp = sI + 50;            // [33]
    int* sEbas = sI + 50 + MAXENT;
    int* sEcnt = sI + 50 + 2 * MAXENT;
    int* sC    = sI + 50 + 3 * MAXENT;

    const int tid = threadIdx.x;
    const int lane = tid & 63, wv = tid >> 6;
    if (tid < NEXP) sHist[tid] = 0;
    __syncthreads();

    // ---- S1: load samples, LDS histogram ----
    const int base0 = blockIdx.x * SAMP;
    float px[S], py[S]; int eid[S], rank[S], gid[S]; bool act[S];
#pragma unroll
    for (int s = 0; s < S; ++s) {
        gid[s] = base0 + s * TPB + tid;               // coalesced float2
        act[s] = gid[s] < N;
        float2 p = act[s] ? samples[gid[s]] : make_float2(0.f, 0.f);
        px[s] = p.x; py[s] = p.y;
        int i = (int)(p.x * (float)GRID_W); i = i < 0 ? 0 : (i > GRID_W - 1 ? GRID_W - 1 : i);
        int j = (int)(p.y * (float)GRID_H); j = j < 0 ? 0 : (j > GRID_H - 1 ? GRID_H - 1 : j);
        eid[s] = j * GRID_W + i;
        rank[s] = act[s] ? atomicAdd(&sHist[eid[s]], 1) : 0;
    }
    __syncthreads();

    // ---- S2: parallel scans in wave 0 ----
    if (wv == 0) {
        int h  = (lane < NEXP) ? sHist[lane] : 0;
        int ec = (lane < NEXP) ? ((h + 63) >> 6) : 0;
        int sh = h, se = ec;
#pragma unroll
        for (int d = 1; d < 16; d <<= 1) {
            int th = __shfl_up(sh, d), te = __shfl_up(se, d);
            if (lane >= d) { sh += th; se += te; }
        }
        if (lane < NEXP) { sOff[lane] = sh - h; sES[lane] = se - ec; }
        if (lane == NEXP - 1) { sOff[NEXP] = sh; sES[NEXP] = se; *sC = se; }
    }
    __syncthreads();

    // ---- S3: scatter sorted slots {h2(x,y), gid} + entry table ----
#pragma unroll
    for (int s = 0; s < S; ++s) {
        if (act[s]) {
            union { h2 h; int i; } u;
            u.h.x = (_Float16)px[s]; u.h.y = (_Float16)py[s];
            int2 v; v.x = u.i; v.y = gid[s];
            sSlot[sOff[eid[s]] + rank[s]] = v;
        }
    }
    int C = *sC;
    if (tid < C) {
        int e = 0;
        while (tid >= sES[e + 1]) ++e;                // <=16 iters, once
        int j = tid - sES[e];
        sEexp[tid] = e;
        sEbas[tid] = sOff[e] + j * GR;
        sEcnt[tid] = min(GR, sHist[e] - j * GR);
    }
    __syncthreads();

    // ---- Phase 2: one entry = one expert-uniform sub-wave; weights via
    // wave-uniform s_load from ws (R6<->R7: scalar pipe == LDS broadcast) ----
    for (int c = wv; c < C; c += NWAVE) {
        int e   = __builtin_amdgcn_readfirstlane(sEexp[c]);
        int bas = __builtin_amdgcn_readfirstlane(sEbas[c]);
        int cnt = __builtin_amdgcn_readfirstlane(sEcnt[c]);

        int2 v = sSlot[bas + lane];                   // padded region: in-bounds
        union { int i; h2 h; } uxy; uxy.i = v.x;
        float x = (float)uxy.h.x, y = (float)uxy.h.y;
        int qg = v.y;

        const float* af = wsAff + e * 12;             // uniform -> s_load
        float y0 = fmaf(x, af[0], fmaf(y, af[1], af[2]));
        float y1 = fmaf(x, af[3], fmaf(y, af[4], af[5]));
        float y2 = fmaf(x, af[6], fmaf(y, af[7], af[8]));

        h2 px2; px2.x = uxy.h.x; px2.y = uxy.h.x;
        h2 py2; py2.x = uxy.h.y; py2.y = uxy.h.y;

        int nb = __builtin_amdgcn_readfirstlane(wsM2[e]);
        const float4* Wm = (const float4*)wsMix + e * F4PE;
        for (int bi = 0; bi < nb; ++bi) {
            H8 A, B, Cc, U0, U1, U2;
            A.f  = Wm[bi];
            B.f  = Wm[F4PA + bi];
            Cc.f = Wm[2 * F4PA + bi];
            U0.f = Wm[3 * F4PA + bi];
            U1.f = Wm[4 * F4PA + bi];
            U2.f = Wm[5 * F4PA + bi];
#pragma unroll
            for (int j = 0; j < 4; ++j) {
                h2 h = __builtin_elementwise_fma(px2, A.p[j],
                       __builtin_elementwise_fma(py2, B.p[j], Cc.p[j]));
                h2 z = (h2)(_Float16)0.0f;
                h = __builtin_elementwise_max(h, z);
#if __has_builtin(__builtin_amdgcn_fdot2)
                y0 = __builtin_amdgcn_fdot2(h, U0.p[j], y0, false);
                y1 = __builtin_amdgcn_fdot2(h, U1.p[j], y1, false);
                y2 = __builtin_amdgcn_fdot2(h, U2.p[j], y2, false);
#else
                y0 += (float)h.x * (float)U0.p[j].x + (float)h.y * (float)U0.p[j].y;
                y1 += (float)h.x * (float)U1.p[j].x + (float)h.y * (float)U1.p[j].y;
                y2 += (float)h.x * (float)U2.p[j].x + (float)h.y * (float)U2.p[j].y;
#endif
            }
        }

        if (lane < cnt) {                             // guard sub-wave padding
            int d = 3 * qg;
            out[d + 0] = y0; out[d + 1] = y1; out[d + 2] = y2;
        }
    }
}

// ---------------------------------------------------------------------------
extern "C" void kernel_launch(void* const* d_in, const int* in_sizes, int n_in,
                              void* d_out, int out_size, void* d_ws, size_t ws_size,
                              hipStream_t stream) {
    const float* samples = (const float*)d_in[0];
    const float* W1      = (const float*)d_in[1];
    const float* b1      = (const float*)d_in[2];
    const float* W2      = (const float*)d_in[3];
    const float* b2      = (const float*)d_in[4];
    float* out = (float*)d_out;

    const int N = in_sizes[0] / 2;
    float*    wsAff = (float*)d_ws;
    int*      wsM2  = (int*)((char*)d_ws + WSOFF_M2);
    _Float16* wsMix = (_Float16*)((char*)d_ws + WSOFF_MIX);

    prep_kernel<<<NEXP, 64, 0, stream>>>(W1, b1, W2, b2, wsAff, wsM2, wsMix);

    const int nblocks = (N + SAMP - 1) / SAMP;        // 512 @ N=524288
    fused_moe_kernel<<<nblocks, TPB, LDS_BYTES, stream>>>(
        (const float2*)samples, wsAff, wsM2, wsMix, out, N);
}